// Round 6
// baseline (1272.565 us; speedup 1.0000x reference)
//
#include <hip/hip_runtime.h>

typedef unsigned short ushort_t;
typedef __attribute__((ext_vector_type(8))) short short8;
typedef __attribute__((ext_vector_type(4))) float floatx4;
typedef __attribute__((ext_vector_type(4))) unsigned int uintx4;

#define BSZ   512
#define UNITS 256
#define IMG   64
#define STEPS 10
#define GATES 1024
// folded ext layout per batch row: [x_hat 4096 | h_dec 256 | h_enc 256]
#define KENC  4608
#define NBLK  256   // persistent grid: one block per CU
#define BK 32
#define FLAG_STRIDE 32                       // 128 B per block flag slot (grid bar)

__device__ inline float b2f(ushort_t u) {
  union { float f; unsigned int i; } v; v.i = ((unsigned int)u) << 16; return v.f;
}
__device__ inline ushort_t f2b(float f) {
  unsigned int u = __float_as_uint(f);
  u += 0x7fffu + ((u >> 16) & 1u);          // round-to-nearest-even
  return (ushort_t)(u >> 16);
}
__device__ inline float sigm(float x) { return 1.f / (1.f + __expf(-x)); }

// Weights: cached global->LDS DMA (aux=0 — proven path).
#define GLL(g, l) __builtin_amdgcn_global_load_lds(                      \
    (const __attribute__((address_space(1))) void*)(g),                  \
    (__attribute__((address_space(3))) void*)(l), 16, 0, 0)

// Coherent scalar ops (relaxed agent atomics -> sc0 sc1, no wbl2/inv) — the
// R2/R3-proven cross-block activation path.
#define CLOADF(p)    __hip_atomic_load((p), __ATOMIC_RELAXED, __HIP_MEMORY_SCOPE_AGENT)
#define CSTOREF(p,v) __hip_atomic_store((p), (v), __ATOMIC_RELAXED, __HIP_MEMORY_SCOPE_AGENT)
#define CSTOREU(p,v) __hip_atomic_store((p), (ushort_t)(v), __ATOMIC_RELAXED, __HIP_MEMORY_SCOPE_AGENT)

// 16B coherent global load (result NOT ready until s_waitcnt vmcnt).
__device__ inline uintx4 cload16(const ushort_t* p) {
  uintx4 r;
  asm volatile("global_load_dwordx4 %0, %1, off sc0 sc1" : "=v"(r) : "v"(p));
  return r;
}
__device__ inline void waitvm0() {
  asm volatile("s_waitcnt vmcnt(0)" ::: "memory");
}
__device__ inline unsigned ldsaddr(const ushort_t* p) {
  return (unsigned)(unsigned long long)(const __attribute__((address_space(3))) void*)p;
}
__device__ inline void dsw16(unsigned off, uintx4 v) {
  asm volatile("ds_write_b128 %0, %1" :: "v"(off), "v"(v));
}

// ---------------------------------------------------------------------------
// Grid barrier (R2/R3-proven): per-block arrival flags (relaxed agent = sc0sc1)
// + leader block 0 aggregation + relaxed generation broadcast. Entry
// __syncthreads drains each wave's vmcnt so sc0sc1 data stores are globally
// visible before the flag rises. Cross-block data is ONLY accessed via sc0sc1.
// ---------------------------------------------------------------------------
__device__ inline void gridbar(unsigned* bar, unsigned id) {
  __syncthreads();
  const int b = blockIdx.x, t = threadIdx.x;
  unsigned* gen = bar + NBLK * FLAG_STRIDE;
  if (b == 0) {
    if (t > 0 && t < NBLK) {
      while (__hip_atomic_load(bar + t * FLAG_STRIDE, __ATOMIC_RELAXED,
                               __HIP_MEMORY_SCOPE_AGENT) < id)
        __builtin_amdgcn_s_sleep(1);
    }
    __syncthreads();
    if (t == 0)
      __hip_atomic_store(gen, id, __ATOMIC_RELAXED, __HIP_MEMORY_SCOPE_AGENT);
  } else if (t == 0) {
    __hip_atomic_store(bar + b * FLAG_STRIDE, id, __ATOMIC_RELAXED,
                       __HIP_MEMORY_SCOPE_AGENT);
    while (__hip_atomic_load(gen, __ATOMIC_RELAXED,
                             __HIP_MEMORY_SCOPE_AGENT) < id)
      __builtin_amdgcn_s_sleep(1);
  }
  __syncthreads();
}

// ---------------------------------------------------------------------------
// Fold patch weights into per-pixel weights + transpose (hi only).
// ---------------------------------------------------------------------------
__global__ __launch_bounds__(256) void k_prep_pix(const float* __restrict__ ek,
                                                  ushort_t* __restrict__ ohi) {
  __shared__ float T[64][68];
  int t = threadIdx.x;
  int pix0 = blockIdx.x * 64, n0 = blockIdx.y * 64;
  int r = t >> 2, seg = t & 3;
  int pix = pix0 + r;
  int ri = pix >> 6, ci = pix & 63;
  float4 acc4[4];
#pragma unroll
  for (int j = 0; j < 4; ++j) acc4[j] = float4{0.f, 0.f, 0.f, 0.f};
#pragma unroll
  for (int di = 0; di < 3; ++di) {
    int ii = ri - di;
    if (ii < 0 || (ii & 1)) continue;
    int oi = ii >> 1;  if (oi >= 32) continue;
#pragma unroll
    for (int dj = 0; dj < 3; ++dj) {
      int jj = ci - dj;
      if (jj < 0 || (jj & 1)) continue;
      int oj = jj >> 1;  if (oj >= 32) continue;
      const float* row = ek + (size_t)((oi * 32 + oj) * 9 + di * 3 + dj) * GATES
                         + n0 + seg * 16;
#pragma unroll
      for (int j = 0; j < 4; ++j) {
        float4 v = *(const float4*)(row + j * 4);
        acc4[j].x += v.x; acc4[j].y += v.y; acc4[j].z += v.z; acc4[j].w += v.w;
      }
    }
  }
#pragma unroll
  for (int j = 0; j < 4; ++j) *(float4*)&T[r][seg * 16 + j * 4] = acc4[j];
  __syncthreads();
  ushort_t thi[16];
#pragma unroll
  for (int j = 0; j < 16; ++j) thi[j] = f2b(T[seg * 16 + j][r]);
  size_t off = (size_t)(n0 + r) * KENC + pix0 + seg * 16;
  *(uint4*)(ohi + off)     = *(const uint4*)&thi[0];
  *(uint4*)(ohi + off + 8) = *(const uint4*)&thi[8];
}

// ---------------------------------------------------------------------------
// Multi-job transpose prep (one dispatch). Also zeroes the grid-barrier words.
// ---------------------------------------------------------------------------
__global__ __launch_bounds__(256) void k_prep_multi(
    const float* __restrict__ ek, const float* __restrict__ er,
    const float* __restrict__ dk, const float* __restrict__ dr,
    const float* __restrict__ Wdec,
    ushort_t* __restrict__ Wet_hi,
    ushort_t* __restrict__ Wdt_hi, ushort_t* __restrict__ Wdt_lo,
    ushort_t* __restrict__ Wct_hi, ushort_t* __restrict__ Wct_lo,
    unsigned* __restrict__ bar) {
  __shared__ float T[64][68];
  int t = threadIdx.x;
  int z = blockIdx.z;
  int k0 = blockIdx.x * 64, n0 = blockIdx.y * 64;
  int r = t >> 2, seg = t & 3;
  if (z == 0) {
    int fid = (blockIdx.y * 4 + blockIdx.x) * 256 + t;
    if (fid <= NBLK * FLAG_STRIDE) bar[fid] = 0u;   // flags + gen
  }

  const float *s0, *s1 = nullptr;
  ushort_t *ohi, *olo = nullptr;
  int src_ld, out_ld, koff;
  if (z == 0) { s0 = ek + (size_t)9216 * GATES; s1 = ek + (size_t)9472 * GATES;
                src_ld = GATES; ohi = Wet_hi; out_ld = KENC; koff = 4096; }
  else if (z == 1) { s0 = er; src_ld = GATES; ohi = Wet_hi; out_ld = KENC; koff = 4352; }
  else if (z == 2) { s0 = dk; src_ld = GATES; ohi = Wdt_hi; olo = Wdt_lo; out_ld = 512; koff = 0; }
  else if (z == 3) { s0 = dr; src_ld = GATES; ohi = Wdt_hi; olo = Wdt_lo; out_ld = 512; koff = 256; }
  else { s0 = Wdec; src_ld = 4096; ohi = Wct_hi; olo = Wct_lo; out_ld = 256; koff = 0;
         n0 += (z - 4) * 1024; }

  const float* src = s0 + (size_t)(k0 + r) * src_ld + n0 + seg * 16;
  const float* src2 = s1 ? (s1 + (size_t)(k0 + r) * src_ld + n0 + seg * 16) : nullptr;
#pragma unroll
  for (int j = 0; j < 4; ++j) {
    float4 v = *(const float4*)(src + j * 4);
    if (src2) {
      float4 w = *(const float4*)(src2 + j * 4);
      v.x += w.x; v.y += w.y; v.z += w.z; v.w += w.w;
    }
    *(float4*)&T[r][seg * 16 + j * 4] = v;
  }
  __syncthreads();
  ushort_t thi[16], tlo[16];
#pragma unroll
  for (int j = 0; j < 16; ++j) {
    float v = T[seg * 16 + j][r];
    ushort_t h = f2b(v);
    thi[j] = h;
    tlo[j] = f2b(v - b2f(h));
  }
  size_t off = (size_t)(n0 + r) * out_ld + koff + k0 + seg * 16;
  *(uint4*)(ohi + off)     = *(const uint4*)&thi[0];
  *(uint4*)(ohi + off + 8) = *(const uint4*)&thi[8];
  if (olo) {
    *(uint4*)(olo + off)     = *(const uint4*)&tlo[0];
    *(uint4*)(olo + off + 8) = *(const uint4*)&tlo[8];
  }
}

// ---------------------------------------------------------------------------
// Persistent kernel: 10 steps, 4 phases/step (LSTM fused into GEMM epilogues
// via 4-region column staging -> each block owns complete units).
// 256 blocks x 512 threads, LDS union 48 KiB.
// ---------------------------------------------------------------------------
__global__ __launch_bounds__(512, 2) void k_persist(
    const float* __restrict__ x,
    const float* __restrict__ ebias, const float* __restrict__ dbias,
    const float* __restrict__ Wenc, const float* __restrict__ benc,
    const float* __restrict__ bdec,
    float* __restrict__ canvas, float* __restrict__ c_enc, float* __restrict__ c_dec,
    float* __restrict__ hbuf,
    ushort_t* __restrict__ ehi, ushort_t* __restrict__ dhi, ushort_t* __restrict__ dlo,
    const ushort_t* __restrict__ Wet_hi,
    const ushort_t* __restrict__ Wdt_hi, const ushort_t* __restrict__ Wdt_lo,
    const ushort_t* __restrict__ Wct_hi, const ushort_t* __restrict__ Wct_lo,
    unsigned* bar) {
  __shared__ __align__(16) ushort_t smem[24576];   // 48 KiB union
  const int b = blockIdx.x, t = threadIdx.x;
  const int lane = t & 63, w = t >> 6;
  const int q = lane >> 4, c16 = lane & 15;
  const int qs = (q ^ ((c16 >> 1) & 3)) * 8;       // swizzled k-seg read offset
  const int half = t >> 8, u8 = t & 255;
  const int rrow = b * 2 + half;
  unsigned barid = 0;

  // ---- preamble: zero state (by OWNER block) + step-0 x_hat --------------
  {
    // canvas: C-block ownership (by=b>>5 rows, bx=b&31 cols)
    const int cby = b >> 5, cbx = b & 31;
    float4* cv4 = (float4*)canvas;
    const float4 z4 = float4{0.f, 0.f, 0.f, 0.f};
#pragma unroll
    for (int j = 0; j < 4; ++j) {
      int idx = j * 512 + t;                 // 2048 float4s = 64 rows x 32
      cv4[(size_t)(cby * 64 + (idx >> 5)) * 1024 + cbx * 32 + (idx & 31)] = z4;
    }
    if (b < 64) {                            // E-owner zeroes its c_enc slice
      const int m0 = (b >> 2) * 32, u0 = (b & 3) * 64;
#pragma unroll
      for (int j = 0; j < 4; ++j) {
        int idx = j * 512 + t;               // 2048 = 32 rows x 64 units
        c_enc[(m0 + (idx >> 6)) * UNITS + u0 + (idx & 63)] = 0.f;
      }
    }
    if (b < 128) {                           // D-owner zeroes its c_dec slice
      const int m0 = (b >> 3) * 32, u0 = (b & 7) * 32;
#pragma unroll
      for (int j = 0; j < 2; ++j) {
        int idx = j * 512 + t;               // 1024 = 32 rows x 32 units
        c_dec[(m0 + (idx >> 5)) * UNITS + u0 + (idx & 31)] = 0.f;
      }
    }
    // sc0sc1 state slots + step-0 x_hat (sigmoid(0)=0.5)
    CSTOREU(ehi + (size_t)rrow * KENC + 4096 + u8, 0);
    CSTOREU(ehi + (size_t)rrow * KENC + 4352 + u8, 0);
    CSTOREU(dhi + (size_t)rrow * 512 + u8, 0);
    CSTOREU(dhi + (size_t)rrow * 512 + 256 + u8, 0);
    CSTOREU(dlo + (size_t)rrow * 512 + u8, 0);
    CSTOREU(dlo + (size_t)rrow * 512 + 256 + u8, 0);
    for (int pix = u8; pix < 4096; pix += 256)
      CSTOREU(ehi + (size_t)rrow * KENC + pix,
              f2b(x[(size_t)rrow * 4096 + pix] - 0.5f));
  }
  gridbar(bar, ++barid);

  for (int s = 0; s < STEPS; ++s) {
    // ===== phase E: enc GEMM full-K + fused LSTM epilogue ===================
    // 64 blocks: bm=b>>2 (M=32 rows), bn=b&3 (64 units x 4 gate-regions).
    if (b < 64) {
      const int m0 = (b >> 2) * 32, u0 = (b & 3) * 64;
      // A staging: t<128, row=t>>2, swizzled seg
      const int ta4 = t >> 2;
      const int sseg = (t & 3) ^ ((t >> 3) & 3);
      const ushort_t* pA = ehi + (size_t)(m0 + (ta4 & 31)) * KENC + sseg * 8;
      // B staging: chunks t and t+512; row=c>>2 in [0,256), 4-region gate cols
      const int brow0 = t >> 2, brow1 = 128 + (t >> 2);
      const int g0 = (brow0 >> 6) * 256 + u0 + (brow0 & 63);
      const int g1 = (brow1 >> 6) * 256 + u0 + (brow1 & 63);
      const ushort_t* pB0 = Wet_hi + (size_t)g0 * KENC + sseg * 8;
      const ushort_t* pB1 = Wet_hi + (size_t)g1 * KENC + sseg * 8;

      floatx4 acc[2][2];
#pragma unroll
      for (int i = 0; i < 2; ++i)
#pragma unroll
        for (int j = 0; j < 2; ++j) acc[i][j] = floatx4{0.f, 0.f, 0.f, 0.f};

      uintx4 va;
      if (t < 128) va = cload16(pA);
      GLL(pB0, &smem[1024 + t * 8]);
      GLL(pB1, &smem[5120 + t * 8]);
      pA += BK; pB0 += BK; pB1 += BK;
      waitvm0();
      if (t < 128) dsw16(ldsaddr(&smem[t * 8]), va);
      __syncthreads();
      for (int kt = 0; kt < 144; ++kt) {
        const int cur = (kt & 1) * 9216, nxt = 9216 - cur;
        if (kt + 1 < 144) {
          if (t < 128) va = cload16(pA);
          GLL(pB0, &smem[nxt + 1024 + t * 8]);
          GLL(pB1, &smem[nxt + 5120 + t * 8]);
          pA += BK; pB0 += BK; pB1 += BK;
        }
        short8 af[2], bf[2];
#pragma unroll
        for (int i = 0; i < 2; ++i)
          af[i] = *(const short8*)&smem[cur + (i * 16 + c16) * BK + qs];
#pragma unroll
        for (int j = 0; j < 2; ++j)
          bf[j] = *(const short8*)&smem[cur + 1024 + (w * 32 + j * 16 + c16) * BK + qs];
#pragma unroll
        for (int mi = 0; mi < 2; ++mi)
#pragma unroll
          for (int ni = 0; ni < 2; ++ni)
            acc[mi][ni] = __builtin_amdgcn_mfma_f32_16x16x32_bf16(af[mi], bf[ni], acc[mi][ni], 0, 0, 0);
        if (kt + 1 < 144) {
          waitvm0();
          if (t < 128) dsw16(ldsaddr(&smem[nxt + t * 8]), va);
        }
        __syncthreads();
      }
      // epilogue: acc -> LDS [32][256] -> per-unit LSTM
      float* zacc = (float*)smem;
#pragma unroll
      for (int mi = 0; mi < 2; ++mi)
#pragma unroll
        for (int ni = 0; ni < 2; ++ni) {
          const int col = w * 32 + ni * 16 + c16;
          const int rowb = mi * 16 + q * 4;
#pragma unroll
          for (int r = 0; r < 4; ++r) zacc[(rowb + r) * 256 + col] = acc[mi][ni][r];
        }
      __syncthreads();
#pragma unroll
      for (int j = 0; j < 4; ++j) {
        const int idx = j * 512 + t;
        const int row = idx >> 6, uu = idx & 63;
        const int un = u0 + uu, rg = m0 + row;
        float zi = zacc[row * 256 + uu]       + ebias[un];
        float zf = zacc[row * 256 + 64 + uu]  + ebias[256 + un];
        float zg = zacc[row * 256 + 128 + uu] + ebias[512 + un];
        float zo = zacc[row * 256 + 192 + uu] + ebias[768 + un];
        float c = c_enc[rg * UNITS + un];
        float cn = sigm(zf) * c + sigm(zi) * tanhf(zg);
        float h = sigm(zo) * tanhf(cn);
        c_enc[rg * UNITS + un] = cn;
        CSTOREU(ehi + (size_t)rg * KENC + 4352 + un, f2b(h));
        CSTOREF(hbuf + (size_t)rg * UNITS + un, h);
      }
    }
    gridbar(bar, ++barid);

    // ===== phase E2: attention softmax + glimpse (2 rows/block) =============
    {
      float* shf = (float*)smem;        // [0,512): h (2 rows); [512,532): logits
      float h = CLOADF(hbuf + (size_t)rrow * UNITS + u8);
      shf[half * 256 + u8] = h;
      __syncthreads();
      if (u8 < 64) {
        float acc[10];
#pragma unroll
        for (int j = 0; j < 10; ++j) acc[j] = 0.f;
        for (int qq = 0; qq < 4; ++qq) {
          float hv = shf[half * 256 + u8 + qq * 64];
          const float* wr = Wenc + (u8 + qq * 64) * 10;
#pragma unroll
          for (int j = 0; j < 10; ++j) acc[j] += hv * wr[j];
        }
        for (int off = 32; off > 0; off >>= 1)
#pragma unroll
          for (int j = 0; j < 10; ++j) acc[j] += __shfl_down(acc[j], off);
        if (u8 == 0)
          for (int j = 0; j < 10; ++j) shf[512 + half * 10 + j] = acc[j] + benc[j];
      }
      __syncthreads();
      float mx = shf[512 + half * 10];
      for (int j = 1; j < 10; ++j) mx = fmaxf(mx, shf[512 + half * 10 + j]);
      float e[10], se = 0.f;
      for (int j = 0; j < 10; ++j) { e[j] = __expf(shf[512 + half * 10 + j] - mx); se += e[j]; }
      float inv = 1.f / se;
      const float* wr = Wenc + u8 * 10;
      float zzv = 0.f;
      for (int j = 0; j < 10; ++j) zzv += e[j] * inv * wr[j];
      ushort_t zh = f2b(zzv);
      CSTOREU(dhi + (size_t)rrow * 512 + u8, zh);
      CSTOREU(dlo + (size_t)rrow * 512 + u8, f2b(zzv - b2f(zh)));
    }
    gridbar(bar, ++barid);

    // ===== phase D: dec GEMM full-K 3-product + fused LSTM epilogue =========
    // 128 blocks: bm=b>>3 (M=32), bn=b&7 (32 units x 4 gate-regions), K=512.
    if (b < 128) {
      const int m0 = (b >> 3) * 32, u0 = (b & 7) * 32;
      const int wm = w >> 2, wn = w & 3;     // 2m(16) x 4n(32) waves
      const int ta2 = t & 127;
      const int sseg = (ta2 & 3) ^ ((ta2 >> 3) & 3);
      const ushort_t* pA = ((t < 128) ? dhi : dlo)
                           + (size_t)(m0 + (ta2 >> 2)) * 512 + sseg * 8;
      const int brow = t >> 2;               // [0,128)
      const int gD = (brow >> 5) * 256 + u0 + (brow & 31);
      const int bsegD = (t & 3) ^ ((t >> 3) & 3);
      const ushort_t* pBh = Wdt_hi + (size_t)gD * 512 + bsegD * 8;
      const ushort_t* pBl = Wdt_lo + (size_t)gD * 512 + bsegD * 8;
      const int dA = ((t < 128) ? 0 : 1024) + ta2 * 8;

      floatx4 acc[2];
      acc[0] = floatx4{0.f, 0.f, 0.f, 0.f};
      acc[1] = floatx4{0.f, 0.f, 0.f, 0.f};

      uintx4 va;
      if (t < 256) va = cload16(pA);
      GLL(pBh, &smem[2048 + t * 8]);
      GLL(pBl, &smem[6144 + t * 8]);
      pA += BK; pBh += BK; pBl += BK;
      waitvm0();
      if (t < 256) dsw16(ldsaddr(&smem[dA]), va);
      __syncthreads();
      for (int kt = 0; kt < 16; ++kt) {
        const int cur = (kt & 1) * 10240, nxt = 10240 - cur;
        if (kt + 1 < 16) {
          if (t < 256) va = cload16(pA);
          GLL(pBh, &smem[nxt + 2048 + t * 8]);
          GLL(pBl, &smem[nxt + 6144 + t * 8]);
          pA += BK; pBh += BK; pBl += BK;
        }
        short8 ah, al, bh[2], bl[2];
        {
          const int ra = (wm * 16 + c16) * BK + qs;
          ah = *(const short8*)&smem[cur + ra];
          al = *(const short8*)&smem[cur + 1024 + ra];
        }
#pragma unroll
        for (int i = 0; i < 2; ++i) {
          const int rb2 = (wn * 32 + i * 16 + c16) * BK + qs;
          bh[i] = *(const short8*)&smem[cur + 2048 + rb2];
          bl[i] = *(const short8*)&smem[cur + 6144 + rb2];
        }
#pragma unroll
        for (int ni = 0; ni < 2; ++ni) {
          acc[ni] = __builtin_amdgcn_mfma_f32_16x16x32_bf16(ah, bh[ni], acc[ni], 0, 0, 0);
          acc[ni] = __builtin_amdgcn_mfma_f32_16x16x32_bf16(ah, bl[ni], acc[ni], 0, 0, 0);
          acc[ni] = __builtin_amdgcn_mfma_f32_16x16x32_bf16(al, bh[ni], acc[ni], 0, 0, 0);
        }
        if (kt + 1 < 16) {
          waitvm0();
          if (t < 256) dsw16(ldsaddr(&smem[nxt + dA]), va);
        }
        __syncthreads();
      }
      // epilogue: acc -> LDS [32][128] -> per-unit LSTM
      float* zacc = (float*)smem;
#pragma unroll
      for (int ni = 0; ni < 2; ++ni) {
        const int col = wn * 32 + ni * 16 + c16;
        const int rowb = wm * 16 + q * 4;
#pragma unroll
        for (int r = 0; r < 4; ++r) zacc[(rowb + r) * 128 + col] = acc[ni][r];
      }
      __syncthreads();
#pragma unroll
      for (int j = 0; j < 2; ++j) {
        const int idx = j * 512 + t;
        const int row = idx >> 5, uu = idx & 31;
        const int un = u0 + uu, rg = m0 + row;
        float zi = zacc[row * 128 + uu]      + dbias[un];
        float zf = zacc[row * 128 + 32 + uu] + dbias[256 + un];
        float zg = zacc[row * 128 + 64 + uu] + dbias[512 + un];
        float zo = zacc[row * 128 + 96 + uu] + dbias[768 + un];
        float c = c_dec[rg * UNITS + un];
        float cn = sigm(zf) * c + sigm(zi) * tanhf(zg);
        float h = sigm(zo) * tanhf(cn);
        c_dec[rg * UNITS + un] = cn;
        ushort_t hh = f2b(h);
        CSTOREU(dhi + (size_t)rg * 512 + 256 + un, hh);
        CSTOREU(dlo + (size_t)rg * 512 + 256 + un, f2b(h - b2f(hh)));
        CSTOREU(ehi + (size_t)rg * KENC + 4096 + un, hh);
      }
    }
    gridbar(bar, ++barid);

    // ===== phase C: canvas GEMM + fused x_hat (R3-proven, 64x128 tiles) =====
    {
      const int by = b >> 5, bx = b & 31;
      const int m0 = by * 64, n0 = bx * 128;
      const int wm = w >> 2, wn = w & 3;
      const int ia = t & 255;
      const int aseg = ((ia & 3) ^ ((ia >> 3) & 3));
      const int bseg = ((t & 3) ^ ((t >> 3) & 3));
      const ushort_t* pA = ((t < 256) ? (dhi + 256) : (dlo + 256))
                           + (size_t)(m0 + (ia >> 2)) * 512 + aseg * 8;
      const ushort_t* pBh = Wct_hi + (size_t)(n0 + (t >> 2)) * 256 + bseg * 8;
      const ushort_t* pBl = Wct_lo + (size_t)(n0 + (t >> 2)) * 256 + bseg * 8;
      const int dA = ((t < 256) ? 0 : 2048) + ia * 8;

      floatx4 acc[2][2];
#pragma unroll
      for (int i = 0; i < 2; ++i)
#pragma unroll
        for (int j = 0; j < 2; ++j) acc[i][j] = floatx4{0.f, 0.f, 0.f, 0.f};

      uintx4 va = cload16(pA);
      GLL(pBh, &smem[4096 + t * 8]);
      GLL(pBl, &smem[8192 + t * 8]);
      pA += BK; pBh += BK; pBl += BK;
      waitvm0();
      dsw16(ldsaddr(&smem[dA]), va);
      __syncthreads();
      for (int kt = 0; kt < 8; ++kt) {
        const int cur = (kt & 1) * 12288, nxt = 12288 - cur;
        if (kt + 1 < 8) {
          va = cload16(pA);
          GLL(pBh, &smem[nxt + 4096 + t * 8]);
          GLL(pBl, &smem[nxt + 8192 + t * 8]);
          pA += BK; pBh += BK; pBl += BK;
        }
        short8 ah[2], al[2], bh[2], bl[2];
#pragma unroll
        for (int i = 0; i < 2; ++i) {
          const int ra = (wm * 32 + i * 16 + c16) * BK + qs;
          ah[i] = *(const short8*)&smem[cur + ra];
          al[i] = *(const short8*)&smem[cur + 2048 + ra];
          const int rb2 = (wn * 32 + i * 16 + c16) * BK + qs;
          bh[i] = *(const short8*)&smem[cur + 4096 + rb2];
          bl[i] = *(const short8*)&smem[cur + 8192 + rb2];
        }
#pragma unroll
        for (int mi = 0; mi < 2; ++mi)
#pragma unroll
          for (int ni = 0; ni < 2; ++ni) {
            acc[mi][ni] = __builtin_amdgcn_mfma_f32_16x16x32_bf16(ah[mi], bh[ni], acc[mi][ni], 0, 0, 0);
            acc[mi][ni] = __builtin_amdgcn_mfma_f32_16x16x32_bf16(ah[mi], bl[ni], acc[mi][ni], 0, 0, 0);
            acc[mi][ni] = __builtin_amdgcn_mfma_f32_16x16x32_bf16(al[mi], bh[ni], acc[mi][ni], 0, 0, 0);
          }
        if (kt + 1 < 8) {
          waitvm0();
          dsw16(ldsaddr(&smem[nxt + dA]), va);
        }
        __syncthreads();
      }
#pragma unroll
      for (int mi = 0; mi < 2; ++mi)
#pragma unroll
        for (int ni = 0; ni < 2; ++ni) {
          const int n = n0 + wn * 32 + ni * 16 + c16;
          const int mb = m0 + wm * 32 + mi * 16 + q * 4;
          const float bv = bdec[n];
#pragma unroll
          for (int r = 0; r < 4; ++r) {
            const int m = mb + r;
            const size_t idx = (size_t)m * 4096 + n;
            const float cv = canvas[idx] + acc[mi][ni][r] + bv;
            canvas[idx] = cv;
            CSTOREU(ehi + (size_t)m * KENC + n, f2b(x[idx] - sigm(cv)));
          }
        }
    }
    if (s + 1 < STEPS) gridbar(bar, ++barid);
  }
}

// ---------------------------------------------------------------------------
extern "C" void kernel_launch(void* const* d_in, const int* in_sizes, int n_in,
                              void* d_out, int out_size, void* d_ws, size_t ws_size,
                              hipStream_t stream) {
  const float* x     = (const float*)d_in[0];
  const float* ek    = (const float*)d_in[1];   // [9728,1024]
  const float* er    = (const float*)d_in[2];   // [256,1024]
  const float* ebias = (const float*)d_in[3];
  const float* dk    = (const float*)d_in[4];   // [256,1024]
  const float* dr    = (const float*)d_in[5];   // [256,1024]
  const float* dbias = (const float*)d_in[6];
  const float* Wenc  = (const float*)d_in[7];   // [256,10]
  const float* benc  = (const float*)d_in[8];
  const float* Wdec  = (const float*)d_in[9];   // [256,4096]
  const float* bdec  = (const float*)d_in[10];

  float* canvas = (float*)d_out;                // [512, 4096] — persistent canvas

  char* p = (char*)d_ws;
  float* c_enc  = (float*)p;        p += (size_t)BSZ * UNITS * 4;
  float* c_dec  = (float*)p;        p += (size_t)BSZ * UNITS * 4;
  float* hbuf   = (float*)p;        p += (size_t)BSZ * UNITS * 4;       // h_enc f32
  ushort_t* ehi = (ushort_t*)p;     p += (size_t)BSZ * KENC * 2;
  ushort_t* dhi = (ushort_t*)p;     p += (size_t)BSZ * 512 * 2;
  ushort_t* dlo = (ushort_t*)p;     p += (size_t)BSZ * 512 * 2;
  ushort_t* Wet_hi = (ushort_t*)p;  p += (size_t)GATES * KENC * 2;      // [1024][4608]
  ushort_t* Wdt_hi = (ushort_t*)p;  p += (size_t)GATES * 512 * 2;       // [1024][512]
  ushort_t* Wdt_lo = (ushort_t*)p;  p += (size_t)GATES * 512 * 2;
  ushort_t* Wct_hi = (ushort_t*)p;  p += (size_t)4096 * UNITS * 2;      // [4096][256]
  ushort_t* Wct_lo = (ushort_t*)p;  p += (size_t)4096 * UNITS * 2;
  unsigned* bar = (unsigned*)p;     p += (size_t)(NBLK * FLAG_STRIDE + 16) * 4;

  // ---- weight prep (once per launch) ----
  k_prep_pix<<<dim3(64, 16), 256, 0, stream>>>(ek, Wet_hi);
  k_prep_multi<<<dim3(4, 16, 8), 256, 0, stream>>>(ek, er, dk, dr, Wdec,
                                                   Wet_hi, Wdt_hi, Wdt_lo,
                                                   Wct_hi, Wct_lo, bar);

  // ---- persistent 10-step kernel (cooperative; fallback to plain launch) ----
  void* args[] = {(void*)&x, (void*)&ebias, (void*)&dbias, (void*)&Wenc,
                  (void*)&benc, (void*)&bdec, (void*)&canvas, (void*)&c_enc,
                  (void*)&c_dec, (void*)&hbuf, (void*)&ehi,
                  (void*)&dhi, (void*)&dlo, (void*)&Wet_hi, (void*)&Wdt_hi,
                  (void*)&Wdt_lo, (void*)&Wct_hi, (void*)&Wct_lo, (void*)&bar};
  if (hipLaunchCooperativeKernel((void*)k_persist, dim3(NBLK), dim3(512),
                                 args, 0, stream) != hipSuccess) {
    k_persist<<<dim3(NBLK), dim3(512), 0, stream>>>(
        x, ebias, dbias, Wenc, benc, bdec, canvas, c_enc, c_dec, hbuf,
        ehi, dhi, dlo, Wet_hi, Wdt_hi, Wdt_lo, Wct_hi, Wct_lo, bar);
  }
}

// Round 7
// 838.640 us; speedup vs baseline: 1.5174x; 1.5174x over previous
//
#include <hip/hip_runtime.h>

typedef unsigned short ushort_t;
typedef __attribute__((ext_vector_type(8))) short short8;
typedef __attribute__((ext_vector_type(4))) float floatx4;
typedef __attribute__((ext_vector_type(4))) unsigned int uintx4;

#define BSZ   512
#define UNITS 256
#define IMG   64
#define STEPS 10
#define GATES 1024
// folded ext layout per batch row: [x_hat 4096 | h_dec 256 | h_enc 256]
#define KENC  4608
#define NBLK  256   // persistent grid: one block per CU
#define BK 32
#define FLAG_STRIDE 32                       // 128 B per block flag slot (grid bar)

__device__ inline float b2f(ushort_t u) {
  union { float f; unsigned int i; } v; v.i = ((unsigned int)u) << 16; return v.f;
}
__device__ inline ushort_t f2b(float f) {
  unsigned int u = __float_as_uint(f);
  u += 0x7fffu + ((u >> 16) & 1u);          // round-to-nearest-even
  return (ushort_t)(u >> 16);
}
__device__ inline float sigm(float x) { return 1.f / (1.f + __expf(-x)); }

// Weights: cached global->LDS DMA (aux=0 — proven path).
#define GLL(g, l) __builtin_amdgcn_global_load_lds(                      \
    (const __attribute__((address_space(1))) void*)(g),                  \
    (__attribute__((address_space(3))) void*)(l), 16, 0, 0)

// Coherent scalar ops (relaxed agent atomics -> sc0 sc1, no wbl2/inv) — the
// R2/R3/R6-proven cross-block activation path.
#define CLOADF(p)    __hip_atomic_load((p), __ATOMIC_RELAXED, __HIP_MEMORY_SCOPE_AGENT)
#define CSTOREF(p,v) __hip_atomic_store((p), (v), __ATOMIC_RELAXED, __HIP_MEMORY_SCOPE_AGENT)
#define CSTOREU(p,v) __hip_atomic_store((p), (ushort_t)(v), __ATOMIC_RELAXED, __HIP_MEMORY_SCOPE_AGENT)

// 16B coherent global load (result NOT ready until s_waitcnt vmcnt).
__device__ inline uintx4 cload16(const ushort_t* p) {
  uintx4 r;
  asm volatile("global_load_dwordx4 %0, %1, off sc0 sc1" : "=v"(r) : "v"(p));
  return r;
}
__device__ inline void waitvm0() {
  asm volatile("s_waitcnt vmcnt(0)" ::: "memory");
}
__device__ inline unsigned ldsaddr(const ushort_t* p) {
  return (unsigned)(unsigned long long)(const __attribute__((address_space(3))) void*)p;
}
__device__ inline void dsw16(unsigned off, uintx4 v) {
  asm volatile("ds_write_b128 %0, %1" :: "v"(off), "v"(v));
}

// ---------------------------------------------------------------------------
// Grid barrier (R2/R3/R6-proven): per-block arrival flags (relaxed agent =
// sc0sc1) + leader block 0 aggregation + relaxed generation broadcast. Entry
// __syncthreads drains each wave's vmcnt so sc0sc1 data stores are globally
// visible before the flag rises. Cross-block data is ONLY accessed via sc0sc1.
// ---------------------------------------------------------------------------
__device__ inline void gridbar(unsigned* bar, unsigned id) {
  __syncthreads();
  const int b = blockIdx.x, t = threadIdx.x;
  unsigned* gen = bar + NBLK * FLAG_STRIDE;
  if (b == 0) {
    if (t > 0 && t < NBLK) {
      while (__hip_atomic_load(bar + t * FLAG_STRIDE, __ATOMIC_RELAXED,
                               __HIP_MEMORY_SCOPE_AGENT) < id)
        __builtin_amdgcn_s_sleep(1);
    }
    __syncthreads();
    if (t == 0)
      __hip_atomic_store(gen, id, __ATOMIC_RELAXED, __HIP_MEMORY_SCOPE_AGENT);
  } else if (t == 0) {
    __hip_atomic_store(bar + b * FLAG_STRIDE, id, __ATOMIC_RELAXED,
                       __HIP_MEMORY_SCOPE_AGENT);
    while (__hip_atomic_load(gen, __ATOMIC_RELAXED,
                             __HIP_MEMORY_SCOPE_AGENT) < id)
      __builtin_amdgcn_s_sleep(1);
  }
  __syncthreads();
}

// ---------------------------------------------------------------------------
// Fold patch weights into per-pixel weights + transpose (hi only).
// ---------------------------------------------------------------------------
__global__ __launch_bounds__(256) void k_prep_pix(const float* __restrict__ ek,
                                                  ushort_t* __restrict__ ohi) {
  __shared__ float T[64][68];
  int t = threadIdx.x;
  int pix0 = blockIdx.x * 64, n0 = blockIdx.y * 64;
  int r = t >> 2, seg = t & 3;
  int pix = pix0 + r;
  int ri = pix >> 6, ci = pix & 63;
  float4 acc4[4];
#pragma unroll
  for (int j = 0; j < 4; ++j) acc4[j] = float4{0.f, 0.f, 0.f, 0.f};
#pragma unroll
  for (int di = 0; di < 3; ++di) {
    int ii = ri - di;
    if (ii < 0 || (ii & 1)) continue;
    int oi = ii >> 1;  if (oi >= 32) continue;
#pragma unroll
    for (int dj = 0; dj < 3; ++dj) {
      int jj = ci - dj;
      if (jj < 0 || (jj & 1)) continue;
      int oj = jj >> 1;  if (oj >= 32) continue;
      const float* row = ek + (size_t)((oi * 32 + oj) * 9 + di * 3 + dj) * GATES
                         + n0 + seg * 16;
#pragma unroll
      for (int j = 0; j < 4; ++j) {
        float4 v = *(const float4*)(row + j * 4);
        acc4[j].x += v.x; acc4[j].y += v.y; acc4[j].z += v.z; acc4[j].w += v.w;
      }
    }
  }
#pragma unroll
  for (int j = 0; j < 4; ++j) *(float4*)&T[r][seg * 16 + j * 4] = acc4[j];
  __syncthreads();
  ushort_t thi[16];
#pragma unroll
  for (int j = 0; j < 16; ++j) thi[j] = f2b(T[seg * 16 + j][r]);
  size_t off = (size_t)(n0 + r) * KENC + pix0 + seg * 16;
  *(uint4*)(ohi + off)     = *(const uint4*)&thi[0];
  *(uint4*)(ohi + off + 8) = *(const uint4*)&thi[8];
}

// ---------------------------------------------------------------------------
// Multi-job transpose prep (one dispatch). Also zeroes the grid-barrier words.
// ---------------------------------------------------------------------------
__global__ __launch_bounds__(256) void k_prep_multi(
    const float* __restrict__ ek, const float* __restrict__ er,
    const float* __restrict__ dk, const float* __restrict__ dr,
    const float* __restrict__ Wdec,
    ushort_t* __restrict__ Wet_hi,
    ushort_t* __restrict__ Wdt_hi, ushort_t* __restrict__ Wdt_lo,
    ushort_t* __restrict__ Wct_hi, ushort_t* __restrict__ Wct_lo,
    unsigned* __restrict__ bar) {
  __shared__ float T[64][68];
  int t = threadIdx.x;
  int z = blockIdx.z;
  int k0 = blockIdx.x * 64, n0 = blockIdx.y * 64;
  int r = t >> 2, seg = t & 3;
  if (z == 0) {
    int fid = (blockIdx.y * 4 + blockIdx.x) * 256 + t;
    if (fid <= NBLK * FLAG_STRIDE) bar[fid] = 0u;   // flags + gen
  }

  const float *s0, *s1 = nullptr;
  ushort_t *ohi, *olo = nullptr;
  int src_ld, out_ld, koff;
  if (z == 0) { s0 = ek + (size_t)9216 * GATES; s1 = ek + (size_t)9472 * GATES;
                src_ld = GATES; ohi = Wet_hi; out_ld = KENC; koff = 4096; }
  else if (z == 1) { s0 = er; src_ld = GATES; ohi = Wet_hi; out_ld = KENC; koff = 4352; }
  else if (z == 2) { s0 = dk; src_ld = GATES; ohi = Wdt_hi; olo = Wdt_lo; out_ld = 512; koff = 0; }
  else if (z == 3) { s0 = dr; src_ld = GATES; ohi = Wdt_hi; olo = Wdt_lo; out_ld = 512; koff = 256; }
  else { s0 = Wdec; src_ld = 4096; ohi = Wct_hi; olo = Wct_lo; out_ld = 256; koff = 0;
         n0 += (z - 4) * 1024; }

  const float* src = s0 + (size_t)(k0 + r) * src_ld + n0 + seg * 16;
  const float* src2 = s1 ? (s1 + (size_t)(k0 + r) * src_ld + n0 + seg * 16) : nullptr;
#pragma unroll
  for (int j = 0; j < 4; ++j) {
    float4 v = *(const float4*)(src + j * 4);
    if (src2) {
      float4 w = *(const float4*)(src2 + j * 4);
      v.x += w.x; v.y += w.y; v.z += w.z; v.w += w.w;
    }
    *(float4*)&T[r][seg * 16 + j * 4] = v;
  }
  __syncthreads();
  ushort_t thi[16], tlo[16];
#pragma unroll
  for (int j = 0; j < 16; ++j) {
    float v = T[seg * 16 + j][r];
    ushort_t h = f2b(v);
    thi[j] = h;
    tlo[j] = f2b(v - b2f(h));
  }
  size_t off = (size_t)(n0 + r) * out_ld + koff + k0 + seg * 16;
  *(uint4*)(ohi + off)     = *(const uint4*)&thi[0];
  *(uint4*)(ohi + off + 8) = *(const uint4*)&thi[8];
  if (olo) {
    *(uint4*)(olo + off)     = *(const uint4*)&tlo[0];
    *(uint4*)(olo + off + 8) = *(const uint4*)&tlo[8];
  }
}

// ---------------------------------------------------------------------------
// Persistent kernel: 10 steps, 4 phases/step.
//  E : enc GEMM split-K 4, 256 blocks (16m x 4u x 4z), partials -> zep
//  E2: LSTM reduce(4) + attention softmax + glimpse (2 rows/block)
//  D : dec GEMM full-K 3-product, 128 blocks, fused dec-LSTM epilogue
//  C : canvas GEMM + fused x_hat, 256 blocks
// ---------------------------------------------------------------------------
__global__ __launch_bounds__(512, 2) void k_persist(
    const float* __restrict__ x,
    const float* __restrict__ ebias, const float* __restrict__ dbias,
    const float* __restrict__ Wenc, const float* __restrict__ benc,
    const float* __restrict__ bdec,
    float* __restrict__ canvas, float* __restrict__ c_enc, float* __restrict__ c_dec,
    float* __restrict__ zep,
    ushort_t* __restrict__ ehi, ushort_t* __restrict__ dhi, ushort_t* __restrict__ dlo,
    const ushort_t* __restrict__ Wet_hi,
    const ushort_t* __restrict__ Wdt_hi, const ushort_t* __restrict__ Wdt_lo,
    const ushort_t* __restrict__ Wct_hi, const ushort_t* __restrict__ Wct_lo,
    unsigned* bar) {
  __shared__ __align__(16) ushort_t smem[24576];   // 48 KiB union
  const int b = blockIdx.x, t = threadIdx.x;
  const int lane = t & 63, w = t >> 6;
  const int q = lane >> 4, c16 = lane & 15;
  const int qs = (q ^ ((c16 >> 1) & 3)) * 8;       // swizzled k-seg read offset
  const int half = t >> 8, u8 = t & 255;
  const int rrow = b * 2 + half;
  unsigned barid = 0;

  // ---- preamble: zero state (by OWNER block) + step-0 x_hat --------------
  {
    // canvas: C-block ownership (by=b>>5 rows, bx=b&31 cols)
    const int cby = b >> 5, cbx = b & 31;
    float4* cv4 = (float4*)canvas;
    const float4 z4 = float4{0.f, 0.f, 0.f, 0.f};
#pragma unroll
    for (int j = 0; j < 4; ++j) {
      int idx = j * 512 + t;                 // 2048 float4s = 64 rows x 32
      cv4[(size_t)(cby * 64 + (idx >> 5)) * 1024 + cbx * 32 + (idx & 31)] = z4;
    }
    // c_enc: E2-owner mapping (block b owns rows b*2, b*2+1)
    c_enc[rrow * UNITS + u8] = 0.f;
    if (b < 128) {                           // D-owner zeroes its c_dec slice
      const int m0 = (b >> 3) * 32, u0 = (b & 7) * 32;
#pragma unroll
      for (int j = 0; j < 2; ++j) {
        int idx = j * 512 + t;               // 1024 = 32 rows x 32 units
        c_dec[(m0 + (idx >> 5)) * UNITS + u0 + (idx & 31)] = 0.f;
      }
    }
    // sc0sc1 state slots + step-0 x_hat (sigmoid(0)=0.5)
    CSTOREU(ehi + (size_t)rrow * KENC + 4096 + u8, 0);
    CSTOREU(ehi + (size_t)rrow * KENC + 4352 + u8, 0);
    CSTOREU(dhi + (size_t)rrow * 512 + u8, 0);
    CSTOREU(dhi + (size_t)rrow * 512 + 256 + u8, 0);
    CSTOREU(dlo + (size_t)rrow * 512 + u8, 0);
    CSTOREU(dlo + (size_t)rrow * 512 + 256 + u8, 0);
    for (int pix = u8; pix < 4096; pix += 256)
      CSTOREU(ehi + (size_t)rrow * KENC + pix,
              f2b(x[(size_t)rrow * 4096 + pix] - 0.5f));
  }
  gridbar(bar, ++barid);

  for (int s = 0; s < STEPS; ++s) {
    // ===== phase E: enc GEMM split-K 4, 256 blocks (16m x 4u x 4z) ==========
    // Tile: M=32 rows, N=256 gate-cols (4 gate regions x 64 units), K=1152.
    {
      const int bm = b & 15, bu = (b >> 4) & 3, bz = b >> 6;
      const int m0 = bm * 32, u0 = bu * 64, kstart = bz * 1152;   // 36 kt
      const int sseg = (t & 3) ^ ((t >> 3) & 3);
      // A staging: t<128, row = t>>2 (0..31)
      const ushort_t* pA = ehi + (size_t)(m0 + ((t >> 2) & 31)) * KENC
                           + kstart + sseg * 8;
      // B staging: 2 chunks/thread; brow = gate-region row in [0,256)
      const int br0 = t >> 2, br1 = 128 + (t >> 2);
      const int g0 = (br0 >> 6) * 256 + u0 + (br0 & 63);
      const int g1 = (br1 >> 6) * 256 + u0 + (br1 & 63);
      const ushort_t* pB0 = Wet_hi + (size_t)g0 * KENC + kstart + sseg * 8;
      const ushort_t* pB1 = Wet_hi + (size_t)g1 * KENC + kstart + sseg * 8;

      floatx4 acc[2][2];
#pragma unroll
      for (int i = 0; i < 2; ++i)
#pragma unroll
        for (int j = 0; j < 2; ++j) acc[i][j] = floatx4{0.f, 0.f, 0.f, 0.f};

      uintx4 va;
      if (t < 128) va = cload16(pA);
      GLL(pB0, &smem[1024 + t * 8]);
      GLL(pB1, &smem[5120 + t * 8]);
      pA += BK; pB0 += BK; pB1 += BK;
      waitvm0();
      if (t < 128) dsw16(ldsaddr(&smem[t * 8]), va);
      __syncthreads();
      for (int kt = 0; kt < 36; ++kt) {
        const int cur = (kt & 1) * 9216, nxt = 9216 - cur;
        if (kt + 1 < 36) {
          if (t < 128) va = cload16(pA);
          GLL(pB0, &smem[nxt + 1024 + t * 8]);
          GLL(pB1, &smem[nxt + 5120 + t * 8]);
          pA += BK; pB0 += BK; pB1 += BK;
        }
        short8 af[2], bf[2];
#pragma unroll
        for (int i = 0; i < 2; ++i)
          af[i] = *(const short8*)&smem[cur + (i * 16 + c16) * BK + qs];
#pragma unroll
        for (int j = 0; j < 2; ++j)
          bf[j] = *(const short8*)&smem[cur + 1024 + (w * 32 + j * 16 + c16) * BK + qs];
#pragma unroll
        for (int mi = 0; mi < 2; ++mi)
#pragma unroll
          for (int ni = 0; ni < 2; ++ni)
            acc[mi][ni] = __builtin_amdgcn_mfma_f32_16x16x32_bf16(af[mi], bf[ni], acc[mi][ni], 0, 0, 0);
        if (kt + 1 < 36) {
          waitvm0();
          if (t < 128) dsw16(ldsaddr(&smem[nxt + t * 8]), va);
        }
        __syncthreads();
      }
      // store partials to zep[row][z][gate*256+unit]
#pragma unroll
      for (int mi = 0; mi < 2; ++mi)
#pragma unroll
        for (int ni = 0; ni < 2; ++ni) {
          const int col = w * 32 + ni * 16 + c16;
          const int gcol = (col >> 6) * 256 + u0 + (col & 63);
          const int rowb = m0 + mi * 16 + q * 4;
#pragma unroll
          for (int r = 0; r < 4; ++r)
            CSTOREF(zep + ((size_t)(rowb + r) * 4 + bz) * 1024 + gcol, acc[mi][ni][r]);
        }
    }
    gridbar(bar, ++barid);

    // ===== phase E2: LSTM reduce(4) + attention + glimpse (2 rows/block) ====
    {
      float* shf = (float*)smem;        // [0,512): h (2 rows); [512,532): logits
      const float* rb = zep + (size_t)rrow * 4096 + u8;
      float v[16];
#pragma unroll
      for (int z = 0; z < 4; ++z)
#pragma unroll
        for (int g = 0; g < 4; ++g)
          v[z * 4 + g] = CLOADF(rb + z * 1024 + g * 256);
      float zi = ebias[u8], zf = ebias[u8 + 256];
      float zg = ebias[u8 + 512], zo = ebias[u8 + 768];
#pragma unroll
      for (int z = 0; z < 4; ++z) {
        zi += v[z * 4]; zf += v[z * 4 + 1]; zg += v[z * 4 + 2]; zo += v[z * 4 + 3];
      }
      float c = c_enc[rrow * UNITS + u8];
      float cn = sigm(zf) * c + sigm(zi) * tanhf(zg);
      float h = sigm(zo) * tanhf(cn);
      c_enc[rrow * UNITS + u8] = cn;
      CSTOREU(ehi + (size_t)rrow * KENC + 4352 + u8, f2b(h));
      shf[half * 256 + u8] = h;
      __syncthreads();
      if (u8 < 64) {    // waves 0 and 4: full-wave shuffle reduce per row
        float acc[10];
#pragma unroll
        for (int j = 0; j < 10; ++j) acc[j] = 0.f;
        for (int qq = 0; qq < 4; ++qq) {
          float hv = shf[half * 256 + u8 + qq * 64];
          const float* wr = Wenc + (u8 + qq * 64) * 10;
#pragma unroll
          for (int j = 0; j < 10; ++j) acc[j] += hv * wr[j];
        }
        for (int off = 32; off > 0; off >>= 1)
#pragma unroll
          for (int j = 0; j < 10; ++j) acc[j] += __shfl_down(acc[j], off);
        if (u8 == 0)
          for (int j = 0; j < 10; ++j) shf[512 + half * 10 + j] = acc[j] + benc[j];
      }
      __syncthreads();
      float mx = shf[512 + half * 10];
      for (int j = 1; j < 10; ++j) mx = fmaxf(mx, shf[512 + half * 10 + j]);
      float e[10], se = 0.f;
      for (int j = 0; j < 10; ++j) { e[j] = __expf(shf[512 + half * 10 + j] - mx); se += e[j]; }
      float inv = 1.f / se;
      const float* wr = Wenc + u8 * 10;
      float zzv = 0.f;
      for (int j = 0; j < 10; ++j) zzv += e[j] * inv * wr[j];
      ushort_t zh = f2b(zzv);
      CSTOREU(dhi + (size_t)rrow * 512 + u8, zh);
      CSTOREU(dlo + (size_t)rrow * 512 + u8, f2b(zzv - b2f(zh)));
    }
    gridbar(bar, ++barid);

    // ===== phase D: dec GEMM full-K 3-product + fused LSTM epilogue =========
    // 128 blocks: bm=b>>3 (M=32), bn=b&7 (32 units x 4 gate-regions), K=512.
    if (b < 128) {
      const int m0 = (b >> 3) * 32, u0 = (b & 7) * 32;
      const int wm = w >> 2, wn = w & 3;     // 2m(16) x 4n(32) waves
      const int ta2 = t & 127;
      const int sseg = (ta2 & 3) ^ ((ta2 >> 3) & 3);
      const ushort_t* pA = ((t < 128) ? dhi : dlo)
                           + (size_t)(m0 + (ta2 >> 2)) * 512 + sseg * 8;
      const int brow = t >> 2;               // [0,128)
      const int gD = (brow >> 5) * 256 + u0 + (brow & 31);
      const int bsegD = (t & 3) ^ ((t >> 3) & 3);
      const ushort_t* pBh = Wdt_hi + (size_t)gD * 512 + bsegD * 8;
      const ushort_t* pBl = Wdt_lo + (size_t)gD * 512 + bsegD * 8;
      const int dA = ((t < 128) ? 0 : 1024) + ta2 * 8;

      floatx4 acc[2];
      acc[0] = floatx4{0.f, 0.f, 0.f, 0.f};
      acc[1] = floatx4{0.f, 0.f, 0.f, 0.f};

      uintx4 va;
      if (t < 256) va = cload16(pA);
      GLL(pBh, &smem[2048 + t * 8]);
      GLL(pBl, &smem[6144 + t * 8]);
      pA += BK; pBh += BK; pBl += BK;
      waitvm0();
      if (t < 256) dsw16(ldsaddr(&smem[dA]), va);
      __syncthreads();
      for (int kt = 0; kt < 16; ++kt) {
        const int cur = (kt & 1) * 10240, nxt = 10240 - cur;
        if (kt + 1 < 16) {
          if (t < 256) va = cload16(pA);
          GLL(pBh, &smem[nxt + 2048 + t * 8]);
          GLL(pBl, &smem[nxt + 6144 + t * 8]);
          pA += BK; pBh += BK; pBl += BK;
        }
        short8 ah, al, bh[2], bl[2];
        {
          const int ra = (wm * 16 + c16) * BK + qs;
          ah = *(const short8*)&smem[cur + ra];
          al = *(const short8*)&smem[cur + 1024 + ra];
        }
#pragma unroll
        for (int i = 0; i < 2; ++i) {
          const int rb2 = (wn * 32 + i * 16 + c16) * BK + qs;
          bh[i] = *(const short8*)&smem[cur + 2048 + rb2];
          bl[i] = *(const short8*)&smem[cur + 6144 + rb2];
        }
#pragma unroll
        for (int ni = 0; ni < 2; ++ni) {
          acc[ni] = __builtin_amdgcn_mfma_f32_16x16x32_bf16(ah, bh[ni], acc[ni], 0, 0, 0);
          acc[ni] = __builtin_amdgcn_mfma_f32_16x16x32_bf16(ah, bl[ni], acc[ni], 0, 0, 0);
          acc[ni] = __builtin_amdgcn_mfma_f32_16x16x32_bf16(al, bh[ni], acc[ni], 0, 0, 0);
        }
        if (kt + 1 < 16) {
          waitvm0();
          if (t < 256) dsw16(ldsaddr(&smem[nxt + dA]), va);
        }
        __syncthreads();
      }
      // epilogue: acc -> LDS [32][128] -> per-unit LSTM
      float* zacc = (float*)smem;
#pragma unroll
      for (int ni = 0; ni < 2; ++ni) {
        const int col = wn * 32 + ni * 16 + c16;
        const int rowb = wm * 16 + q * 4;
#pragma unroll
        for (int r = 0; r < 4; ++r) zacc[(rowb + r) * 128 + col] = acc[ni][r];
      }
      __syncthreads();
#pragma unroll
      for (int j = 0; j < 2; ++j) {
        const int idx = j * 512 + t;
        const int row = idx >> 5, uu = idx & 31;
        const int un = u0 + uu, rg = m0 + row;
        float zi = zacc[row * 128 + uu]      + dbias[un];
        float zf = zacc[row * 128 + 32 + uu] + dbias[256 + un];
        float zg = zacc[row * 128 + 64 + uu] + dbias[512 + un];
        float zo = zacc[row * 128 + 96 + uu] + dbias[768 + un];
        float c = c_dec[rg * UNITS + un];
        float cn = sigm(zf) * c + sigm(zi) * tanhf(zg);
        float h = sigm(zo) * tanhf(cn);
        c_dec[rg * UNITS + un] = cn;
        ushort_t hh = f2b(h);
        CSTOREU(dhi + (size_t)rg * 512 + 256 + un, hh);
        CSTOREU(dlo + (size_t)rg * 512 + 256 + un, f2b(h - b2f(hh)));
        CSTOREU(ehi + (size_t)rg * KENC + 4096 + un, hh);
      }
    }
    gridbar(bar, ++barid);

    // ===== phase C: canvas GEMM + fused x_hat (proven, 64x128 tiles) ========
    {
      const int by = b >> 5, bx = b & 31;
      const int m0 = by * 64, n0 = bx * 128;
      const int wm = w >> 2, wn = w & 3;
      const int ia = t & 255;
      const int aseg = ((ia & 3) ^ ((ia >> 3) & 3));
      const int bseg = ((t & 3) ^ ((t >> 3) & 3));
      const ushort_t* pA = ((t < 256) ? (dhi + 256) : (dlo + 256))
                           + (size_t)(m0 + (ia >> 2)) * 512 + aseg * 8;
      const ushort_t* pBh = Wct_hi + (size_t)(n0 + (t >> 2)) * 256 + bseg * 8;
      const ushort_t* pBl = Wct_lo + (size_t)(n0 + (t >> 2)) * 256 + bseg * 8;
      const int dA = ((t < 256) ? 0 : 2048) + ia * 8;

      floatx4 acc[2][2];
#pragma unroll
      for (int i = 0; i < 2; ++i)
#pragma unroll
        for (int j = 0; j < 2; ++j) acc[i][j] = floatx4{0.f, 0.f, 0.f, 0.f};

      uintx4 va = cload16(pA);
      GLL(pBh, &smem[4096 + t * 8]);
      GLL(pBl, &smem[8192 + t * 8]);
      pA += BK; pBh += BK; pBl += BK;
      waitvm0();
      dsw16(ldsaddr(&smem[dA]), va);
      __syncthreads();
      for (int kt = 0; kt < 8; ++kt) {
        const int cur = (kt & 1) * 12288, nxt = 12288 - cur;
        if (kt + 1 < 8) {
          va = cload16(pA);
          GLL(pBh, &smem[nxt + 4096 + t * 8]);
          GLL(pBl, &smem[nxt + 8192 + t * 8]);
          pA += BK; pBh += BK; pBl += BK;
        }
        short8 ah[2], al[2], bh[2], bl[2];
#pragma unroll
        for (int i = 0; i < 2; ++i) {
          const int ra = (wm * 32 + i * 16 + c16) * BK + qs;
          ah[i] = *(const short8*)&smem[cur + ra];
          al[i] = *(const short8*)&smem[cur + 2048 + ra];
          const int rb2 = (wn * 32 + i * 16 + c16) * BK + qs;
          bh[i] = *(const short8*)&smem[cur + 4096 + rb2];
          bl[i] = *(const short8*)&smem[cur + 8192 + rb2];
        }
#pragma unroll
        for (int mi = 0; mi < 2; ++mi)
#pragma unroll
          for (int ni = 0; ni < 2; ++ni) {
            acc[mi][ni] = __builtin_amdgcn_mfma_f32_16x16x32_bf16(ah[mi], bh[ni], acc[mi][ni], 0, 0, 0);
            acc[mi][ni] = __builtin_amdgcn_mfma_f32_16x16x32_bf16(ah[mi], bl[ni], acc[mi][ni], 0, 0, 0);
            acc[mi][ni] = __builtin_amdgcn_mfma_f32_16x16x32_bf16(al[mi], bh[ni], acc[mi][ni], 0, 0, 0);
          }
        if (kt + 1 < 8) {
          waitvm0();
          dsw16(ldsaddr(&smem[nxt + dA]), va);
        }
        __syncthreads();
      }
#pragma unroll
      for (int mi = 0; mi < 2; ++mi)
#pragma unroll
        for (int ni = 0; ni < 2; ++ni) {
          const int n = n0 + wn * 32 + ni * 16 + c16;
          const int mb = m0 + wm * 32 + mi * 16 + q * 4;
          const float bv = bdec[n];
#pragma unroll
          for (int r = 0; r < 4; ++r) {
            const int m = mb + r;
            const size_t idx = (size_t)m * 4096 + n;
            const float cv = canvas[idx] + acc[mi][ni][r] + bv;
            canvas[idx] = cv;
            CSTOREU(ehi + (size_t)m * KENC + n, f2b(x[idx] - sigm(cv)));
          }
        }
    }
    if (s + 1 < STEPS) gridbar(bar, ++barid);
  }
}

// ---------------------------------------------------------------------------
extern "C" void kernel_launch(void* const* d_in, const int* in_sizes, int n_in,
                              void* d_out, int out_size, void* d_ws, size_t ws_size,
                              hipStream_t stream) {
  const float* x     = (const float*)d_in[0];
  const float* ek    = (const float*)d_in[1];   // [9728,1024]
  const float* er    = (const float*)d_in[2];   // [256,1024]
  const float* ebias = (const float*)d_in[3];
  const float* dk    = (const float*)d_in[4];   // [256,1024]
  const float* dr    = (const float*)d_in[5];   // [256,1024]
  const float* dbias = (const float*)d_in[6];
  const float* Wenc  = (const float*)d_in[7];   // [256,10]
  const float* benc  = (const float*)d_in[8];
  const float* Wdec  = (const float*)d_in[9];   // [256,4096]
  const float* bdec  = (const float*)d_in[10];

  float* canvas = (float*)d_out;                // [512, 4096] — persistent canvas

  char* p = (char*)d_ws;
  float* c_enc  = (float*)p;        p += (size_t)BSZ * UNITS * 4;
  float* c_dec  = (float*)p;        p += (size_t)BSZ * UNITS * 4;
  float* zep    = (float*)p;        p += (size_t)4 * BSZ * GATES * 4;   // [row][4][1024]
  ushort_t* ehi = (ushort_t*)p;     p += (size_t)BSZ * KENC * 2;
  ushort_t* dhi = (ushort_t*)p;     p += (size_t)BSZ * 512 * 2;
  ushort_t* dlo = (ushort_t*)p;     p += (size_t)BSZ * 512 * 2;
  ushort_t* Wet_hi = (ushort_t*)p;  p += (size_t)GATES * KENC * 2;      // [1024][4608]
  ushort_t* Wdt_hi = (ushort_t*)p;  p += (size_t)GATES * 512 * 2;       // [1024][512]
  ushort_t* Wdt_lo = (ushort_t*)p;  p += (size_t)GATES * 512 * 2;
  ushort_t* Wct_hi = (ushort_t*)p;  p += (size_t)4096 * UNITS * 2;      // [4096][256]
  ushort_t* Wct_lo = (ushort_t*)p;  p += (size_t)4096 * UNITS * 2;
  unsigned* bar = (unsigned*)p;     p += (size_t)(NBLK * FLAG_STRIDE + 16) * 4;

  // ---- weight prep (once per launch) ----
  k_prep_pix<<<dim3(64, 16), 256, 0, stream>>>(ek, Wet_hi);
  k_prep_multi<<<dim3(4, 16, 8), 256, 0, stream>>>(ek, er, dk, dr, Wdec,
                                                   Wet_hi, Wdt_hi, Wdt_lo,
                                                   Wct_hi, Wct_lo, bar);

  // ---- persistent 10-step kernel (cooperative; fallback to plain launch) ----
  void* args[] = {(void*)&x, (void*)&ebias, (void*)&dbias, (void*)&Wenc,
                  (void*)&benc, (void*)&bdec, (void*)&canvas, (void*)&c_enc,
                  (void*)&c_dec, (void*)&zep, (void*)&ehi,
                  (void*)&dhi, (void*)&dlo, (void*)&Wet_hi, (void*)&Wdt_hi,
                  (void*)&Wdt_lo, (void*)&Wct_hi, (void*)&Wct_lo, (void*)&bar};
  if (hipLaunchCooperativeKernel((void*)k_persist, dim3(NBLK), dim3(512),
                                 args, 0, stream) != hipSuccess) {
    k_persist<<<dim3(NBLK), dim3(512), 0, stream>>>(
        x, ebias, dbias, Wenc, benc, bdec, canvas, c_enc, c_dec, zep,
        ehi, dhi, dlo, Wet_hi, Wdt_hi, Wdt_lo, Wct_hi, Wct_lo, bar);
  }
}